// Round 13
// baseline (3049.579 us; speedup 1.0000x reference)
//
#include <hip/hip_runtime.h>
#include <math.h>

#define VOCAB 50000
#define EMB 256
#define HID 512
#define G4 2048   // 4*HID
#define KTAGS 20
#define START_TAG 18
#define END_TAG 19
#define BB 32
#define TT 256
#define NEGV -10000.0f
#define HSROW 644   // 640 phys floats per row + 4 skew

typedef float v4f __attribute__((ext_vector_type(4)));

__device__ __forceinline__ float sigmoidf_(float x) { return 1.0f / (1.0f + expf(-x)); }

// ---------------------------------------------------------------------------
// K1: pre[dir][b][t][j] = emb[tok(b,t,dir)] . Wih[j,:] + bih[j] + bhh[j]
// ---------------------------------------------------------------------------
__global__ __launch_bounds__(256) void k_pre_gemm(
    const int* __restrict__ sentence, const int* __restrict__ lengths,
    const float* __restrict__ emb,
    const float* __restrict__ Wf_ih, const float* __restrict__ bf_ih, const float* __restrict__ bf_hh,
    const float* __restrict__ Wb_ih, const float* __restrict__ bb_ih, const float* __restrict__ bb_hh,
    float* __restrict__ pre)
{
    const int m0 = blockIdx.y * 64;
    if ((m0 & 255) >= lengths[m0 >> 8]) return;   // whole tile padded -> unread

    const int dir = blockIdx.z;
    const float* W  = dir ? Wb_ih : Wf_ih;   // [2048][256]
    const float* b1 = dir ? bb_ih : bf_ih;
    const float* b2 = dir ? bb_hh : bf_hh;
    float* C = pre + (size_t)dir * BB * TT * G4;

    __shared__ float As[64][17];
    __shared__ float Bs[64][17];

    const int tid = threadIdx.x;
    const int n0 = blockIdx.x * 64;

    const int lr = tid >> 2;
    const int lq = tid & 3;

    const int m    = m0 + lr;
    const int bidx = m >> 8;
    const int trow = m & 255;
    int pos = trow;
    if (dir) {
        int len = lengths[bidx];
        pos = (trow < len) ? (len - 1 - trow) : trow;
    }
    const int tok = sentence[bidx * TT + pos];
    const float* arow = emb + (size_t)tok * EMB;
    const float* wrow = W + (size_t)(n0 + lr) * EMB;

    const int ty = tid >> 4;
    const int tx = tid & 15;

    float acc[4][4];
    #pragma unroll
    for (int i = 0; i < 4; i++)
        #pragma unroll
        for (int j = 0; j < 4; j++) acc[i][j] = 0.f;

    for (int k0 = 0; k0 < EMB; k0 += 16) {
        float4 av = *(const float4*)(arow + k0 + lq * 4);
        float4 bv = *(const float4*)(wrow + k0 + lq * 4);
        As[lr][lq * 4 + 0] = av.x; As[lr][lq * 4 + 1] = av.y;
        As[lr][lq * 4 + 2] = av.z; As[lr][lq * 4 + 3] = av.w;
        Bs[lr][lq * 4 + 0] = bv.x; Bs[lr][lq * 4 + 1] = bv.y;
        Bs[lr][lq * 4 + 2] = bv.z; Bs[lr][lq * 4 + 3] = bv.w;
        __syncthreads();
        #pragma unroll
        for (int kk = 0; kk < 16; kk++) {
            float a[4], bb_[4];
            #pragma unroll
            for (int i = 0; i < 4; i++) a[i] = As[ty * 4 + i][kk];
            #pragma unroll
            for (int j = 0; j < 4; j++) bb_[j] = Bs[tx * 4 + j][kk];
            #pragma unroll
            for (int i = 0; i < 4; i++)
                #pragma unroll
                for (int j = 0; j < 4; j++)
                    acc[i][j] = fmaf(a[i], bb_[j], acc[i][j]);
        }
        __syncthreads();
    }

    float bs[4];
    #pragma unroll
    for (int j = 0; j < 4; j++) {
        int n = n0 + tx * 4 + j;
        bs[j] = b1[n] + b2[n];
    }
    #pragma unroll
    for (int i = 0; i < 4; i++) {
        int row = m0 + ty * 4 + i;
        float* cp = C + (size_t)row * G4 + n0 + tx * 4;
        #pragma unroll
        for (int j = 0; j < 4; j++) cp[j] = acc[i][j] + bs[j];
    }
}

// ---------------------------------------------------------------------------
// K2: persistent batched LSTM — BARRIER-FREE tagged dataflow.
//   256 WGs x 512 thr (1/CU). WG = (8-unit slice, 8-batch sorted group),
//   both dirs. Exchange granule: 16B chunk = {h[2u], h[2u+1], pad, tag},
//   written by ONE lane as a single dwordx4 sc1 store (atomic transaction:
//   tag visible <=> data visible). Consumer staging loads poll tag==t and
//   consume data from the same load — zero separate barrier RTs.
//   Safety: a WG finishes step-t staging only after ALL cohort peers stored
//   tag t (end of their step t-1); tag t-1 consumption precedes tag t
//   production, so skew <= 1 step and 2 parity buffers suffice. Tags strictly
//   increase (no ABA). t=0 expects tag 0 = memset.
// ---------------------------------------------------------------------------
__global__ __launch_bounds__(512, 1) void k_lstm_persist(
    const int* __restrict__ lengths,
    const float* __restrict__ Wf_hh, const float* __restrict__ Wb_hh,
    const float* __restrict__ pre,     // [2][32][256][2048]
    float* __restrict__ hp2,           // [2 parity][2 dir][32][256 chunks x 16B]
    float* __restrict__ hbuf)          // [2][32][256][512]
{
    const int wg = blockIdx.x;             // 0..255
    const int slice = wg >> 2;             // unit slice 0..63
    const int grp = wg & 3;                // sorted batch group 0..3
    const int tid = threadIdx.x;
    const int wave = tid >> 6;             // dot: local unit; gate: batch row
    const int lane = tid & 63;
    const int u_glob = slice * 8 + wave;

    float4 wF[4][2], wB[4][2];
    #pragma unroll
    for (int c = 0; c < 4; c++) {
        const float4* wr = (const float4*)(Wf_hh + (size_t)(c * HID + u_glob) * HID + lane * 8);
        wF[c][0] = wr[0]; wF[c][1] = wr[1];
        const float4* wr2 = (const float4*)(Wb_hh + (size_t)(c * HID + u_glob) * HID + lane * 8);
        wB[c][0] = wr2[0]; wB[c][1] = wr2[1];
    }

    __shared__ float hs[16 * HSROW];       // rows 0-7: F batches, 8-15: B batches
    __shared__ float zw[16 * 132];         // [dir*8 + u_loc][gate*33 + j]
    __shared__ int lens_raw[32];
    __shared__ int order_s[32];
    __shared__ int lens_s[32];
    __shared__ int nbt_s[TT];

    if (tid < 32) lens_raw[tid] = lengths[tid];
    __syncthreads();
    if (tid < 32) {
        int me = lens_raw[tid], rank = 0;
        #pragma unroll 4
        for (int o = 0; o < 32; o++) {
            int lo = lens_raw[o];
            rank += (lo > me || (lo == me && o < tid)) ? 1 : 0;
        }
        order_s[rank] = tid;
        lens_s[rank] = me;
    }
    if (tid >= 256) {
        int t = tid - 256, c = 0;
        #pragma unroll 4
        for (int b = 0; b < 32; b++) c += (lens_raw[b] > t) ? 1 : 0;
        nbt_s[t] = c;
    }
    __syncthreads();

    const int tlimit = lens_s[grp * 8];

    // ---- staging identity: 8 slots/thread; slot i -> row16 = 2i + (tid>>8),
    //      col = tid & 255 (chunk index). Chunk col holds units 2col,2col+1.
    const int col = tid & 255;
    const int rhalf = tid >> 8;            // 0..1
    int srow[8]; int sbat[8]; int sj[8]; int sdst[8];
    #pragma unroll
    for (int i = 0; i < 8; i++) {
        int row16 = 2 * i + rhalf;
        srow[i] = row16;
        sj[i] = row16 & 7;
        sbat[i] = order_s[grp * 8 + (row16 & 7)];
        sdst[i] = row16 * HSROW + 2 * col + 4 * (col >> 3);
    }

    // ---- gate identity: wave = batch row, lanes 0-3 = 2 units each ----
    const int ln = lane;                   // use lanes 0..3
    const int g_act_lane = (ln < 4);
    const int mylen_w = lens_s[grp * 8 + wave];
    const int mybat_w = order_s[grp * 8 + wave];
    const int u0 = slice * 8 + 2 * ln;     // first of this lane's 2 units
    const int chunk_idx = slice * 4 + ln;  // global chunk for these 2 units
    const float* preF_w = pre + (size_t)mybat_w * TT * G4 + u0;
    const float* preB_w = pre + (size_t)(BB + mybat_w) * TT * G4 + u0;
    float* houtF_w = hbuf + (size_t)mybat_w * TT * HID + u0;
    float* houtB_w = hbuf + (size_t)(BB + mybat_w) * TT * HID + u0;

    const int rdoff = 8 * lane + 4 * (lane >> 1);

    float cF0 = 0.f, cF1 = 0.f, cB0 = 0.f, cB1 = 0.f;

#define DOTRED(WREG, ROWOFF, ZOFF)                                             \
    for (int j = 0; j < jmax; j++) {                                           \
        const float* hb = &hs[((ROWOFF) + j) * HSROW + rdoff];                 \
        float4 h0 = *(const float4*)(hb);                                      \
        float4 h1 = *(const float4*)(hb + 4);                                  \
        float a0 = 0.f, a1 = 0.f, a2 = 0.f, a3 = 0.f;                          \
        a0 = fmaf(WREG[0][0].x, h0.x, a0); a0 = fmaf(WREG[0][0].y, h0.y, a0);  \
        a0 = fmaf(WREG[0][0].z, h0.z, a0); a0 = fmaf(WREG[0][0].w, h0.w, a0);  \
        a0 = fmaf(WREG[0][1].x, h1.x, a0); a0 = fmaf(WREG[0][1].y, h1.y, a0);  \
        a0 = fmaf(WREG[0][1].z, h1.z, a0); a0 = fmaf(WREG[0][1].w, h1.w, a0);  \
        a1 = fmaf(WREG[1][0].x, h0.x, a1); a1 = fmaf(WREG[1][0].y, h0.y, a1);  \
        a1 = fmaf(WREG[1][0].z, h0.z, a1); a1 = fmaf(WREG[1][0].w, h0.w, a1);  \
        a1 = fmaf(WREG[1][1].x, h1.x, a1); a1 = fmaf(WREG[1][1].y, h1.y, a1);  \
        a1 = fmaf(WREG[1][1].z, h1.z, a1); a1 = fmaf(WREG[1][1].w, h1.w, a1);  \
        a2 = fmaf(WREG[2][0].x, h0.x, a2); a2 = fmaf(WREG[2][0].y, h0.y, a2);  \
        a2 = fmaf(WREG[2][0].z, h0.z, a2); a2 = fmaf(WREG[2][0].w, h0.w, a2);  \
        a2 = fmaf(WREG[2][1].x, h1.x, a2); a2 = fmaf(WREG[2][1].y, h1.y, a2);  \
        a2 = fmaf(WREG[2][1].z, h1.z, a2); a2 = fmaf(WREG[2][1].w, h1.w, a2);  \
        a3 = fmaf(WREG[3][0].x, h0.x, a3); a3 = fmaf(WREG[3][0].y, h0.y, a3);  \
        a3 = fmaf(WREG[3][0].z, h0.z, a3); a3 = fmaf(WREG[3][0].w, h0.w, a3);  \
        a3 = fmaf(WREG[3][1].x, h1.x, a3); a3 = fmaf(WREG[3][1].y, h1.y, a3);  \
        a3 = fmaf(WREG[3][1].z, h1.z, a3); a3 = fmaf(WREG[3][1].w, h1.w, a3);  \
        bool lo32 = (lane & 32) == 0;                                          \
        float tA = __shfl_xor(lo32 ? a2 : a0, 32);                             \
        float tB = __shfl_xor(lo32 ? a3 : a1, 32);                             \
        float rAq = (lo32 ? a0 : a2) + tA;                                     \
        float rBq = (lo32 ? a1 : a3) + tB;                                     \
        bool lo16 = (lane & 16) == 0;                                          \
        float tC = __shfl_xor(lo16 ? rBq : rAq, 16);                           \
        float r  = (lo16 ? rAq : rBq) + tC;                                    \
        r += __shfl_xor(r, 8);                                                 \
        r += __shfl_xor(r, 4);                                                 \
        r += __shfl_xor(r, 2);                                                 \
        r += __shfl_xor(r, 1);                                                 \
        if ((lane & 15) == 0)                                                  \
            zw[((ZOFF) + wave) * 132 + (lane >> 4) * 33 + j] = r;              \
    }

    for (int t = 0; t < tlimit; t++) {
        const int nbt = nbt_s[t];
        const int jmax = min(max(nbt - grp * 8, 0), 8);
        const int act = g_act_lane && (t < mylen_w);

        // ---- early-issue pre-activation loads (both dirs, float2 per gate) ----
        float2 pF[4], pB[4];
        #pragma unroll
        for (int c = 0; c < 4; c++) { pF[c] = make_float2(0.f, 0.f); pB[c] = pF[c]; }
        if (act) {
            #pragma unroll
            for (int c = 0; c < 4; c++) {
                pF[c] = *(const float2*)(preF_w + (size_t)t * G4 + c * HID);
                pB[c] = *(const float2*)(preB_w + (size_t)t * G4 + c * HID);
            }
        }

        // ---- stage h(t): tagged poll loads (the barrier IS the data) ----
        {
            const char* pbase = (const char*)hp2 + (size_t)((t & 1) * 2) * BB * 4096;
            const char* a0 = pbase + ((size_t)(srow[0] >> 3) * BB + sbat[0]) * 4096 + col * 16;
            const char* a1 = pbase + ((size_t)(srow[1] >> 3) * BB + sbat[1]) * 4096 + col * 16;
            const char* a2 = pbase + ((size_t)(srow[2] >> 3) * BB + sbat[2]) * 4096 + col * 16;
            const char* a3 = pbase + ((size_t)(srow[3] >> 3) * BB + sbat[3]) * 4096 + col * 16;
            const char* a4 = pbase + ((size_t)(srow[4] >> 3) * BB + sbat[4]) * 4096 + col * 16;
            const char* a5 = pbase + ((size_t)(srow[5] >> 3) * BB + sbat[5]) * 4096 + col * 16;
            const char* a6 = pbase + ((size_t)(srow[6] >> 3) * BB + sbat[6]) * 4096 + col * 16;
            const char* a7 = pbase + ((size_t)(srow[7] >> 3) * BB + sbat[7]) * 4096 + col * 16;
            bool req[8];
            #pragma unroll
            for (int i = 0; i < 8; i++) req[i] = (grp * 8 + sj[i] < nbt);
            const unsigned expv = (unsigned)t;
            float4 u0v, u1v, u2v, u3v, u4v, u5v, u6v, u7v;
            while (true) {
                asm volatile(
                    "global_load_dwordx4 %0, %8, off sc0 sc1\n\t"
                    "global_load_dwordx4 %1, %9, off sc0 sc1\n\t"
                    "global_load_dwordx4 %2, %10, off sc0 sc1\n\t"
                    "global_load_dwordx4 %3, %11, off sc0 sc1\n\t"
                    "global_load_dwordx4 %4, %12, off sc0 sc1\n\t"
                    "global_load_dwordx4 %5, %13, off sc0 sc1\n\t"
                    "global_load_dwordx4 %6, %14, off sc0 sc1\n\t"
                    "global_load_dwordx4 %7, %15, off sc0 sc1\n\t"
                    "s_waitcnt vmcnt(0)"
                    : "=&v"(u0v), "=&v"(u1v), "=&v"(u2v), "=&v"(u3v),
                      "=&v"(u4v), "=&v"(u5v), "=&v"(u6v), "=&v"(u7v)
                    : "v"(a0), "v"(a1), "v"(a2), "v"(a3),
                      "v"(a4), "v"(a5), "v"(a6), "v"(a7)
                    : "memory");
                bool ok = true;
                if (req[0] && __float_as_uint(u0v.w) != expv) ok = false;
                if (req[1] && __float_as_uint(u1v.w) != expv) ok = false;
                if (req[2] && __float_as_uint(u2v.w) != expv) ok = false;
                if (req[3] && __float_as_uint(u3v.w) != expv) ok = false;
                if (req[4] && __float_as_uint(u4v.w) != expv) ok = false;
                if (req[5] && __float_as_uint(u5v.w) != expv) ok = false;
                if (req[6] && __float_as_uint(u6v.w) != expv) ok = false;
                if (req[7] && __float_as_uint(u7v.w) != expv) ok = false;
                if (ok) break;
                __builtin_amdgcn_s_sleep(1);
            }
            *(float2*)&hs[sdst[0]] = make_float2(u0v.x, u0v.y);
            *(float2*)&hs[sdst[1]] = make_float2(u1v.x, u1v.y);
            *(float2*)&hs[sdst[2]] = make_float2(u2v.x, u2v.y);
            *(float2*)&hs[sdst[3]] = make_float2(u3v.x, u3v.y);
            *(float2*)&hs[sdst[4]] = make_float2(u4v.x, u4v.y);
            *(float2*)&hs[sdst[5]] = make_float2(u5v.x, u5v.y);
            *(float2*)&hs[sdst[6]] = make_float2(u6v.x, u6v.y);
            *(float2*)&hs[sdst[7]] = make_float2(u7v.x, u7v.y);
        }
        __syncthreads();                       // hs ready (also: zw free for dot)

        // ---- dots: F then B ----
        DOTRED(wF, 0, 0);
        DOTRED(wB, 8, 8);
        __syncthreads();                       // zw ready; hs free for next stage

        // ---- gate: wave = batch row, lane 0-3 = 2 units; tagged h-store ----
        if (act) {
            const float tagf = __uint_as_float((unsigned)(t + 1));
            // forward
            {
                float h2[2];
                #pragma unroll
                for (int e = 0; e < 2; e++) {
                    const int zr = (2 * ln + e) * 132 + wave;
                    float iv = zw[zr +  0] + (e ? pF[0].y : pF[0].x);
                    float fv = zw[zr + 33] + (e ? pF[1].y : pF[1].x);
                    float gv = zw[zr + 66] + (e ? pF[2].y : pF[2].x);
                    float ov = zw[zr + 99] + (e ? pF[3].y : pF[3].x);
                    float cold = e ? cF1 : cF0;
                    float cn = sigmoidf_(fv) * cold + sigmoidf_(iv) * tanhf(gv);
                    float hn = sigmoidf_(ov) * tanhf(cn);
                    if (e) cF1 = cn; else cF0 = cn;
                    h2[e] = hn;
                }
                *(float2*)(houtF_w + (size_t)t * HID) = make_float2(h2[0], h2[1]);
                v4f sv; sv.x = h2[0]; sv.y = h2[1]; sv.z = 0.f; sv.w = tagf;
                const char* ad = (const char*)hp2
                    + ((size_t)(((t + 1) & 1) * 2 + 0) * BB + mybat_w) * 4096 + chunk_idx * 16;
                asm volatile("global_store_dwordx4 %0, %1, off sc0 sc1"
                             :: "v"(ad), "v"(sv) : "memory");
            }
            // backward
            {
                float h2[2];
                #pragma unroll
                for (int e = 0; e < 2; e++) {
                    const int zr = (8 + 2 * ln + e) * 132 + wave;
                    float iv = zw[zr +  0] + (e ? pB[0].y : pB[0].x);
                    float fv = zw[zr + 33] + (e ? pB[1].y : pB[1].x);
                    float gv = zw[zr + 66] + (e ? pB[2].y : pB[2].x);
                    float ov = zw[zr + 99] + (e ? pB[3].y : pB[3].x);
                    float cold = e ? cB1 : cB0;
                    float cn = sigmoidf_(fv) * cold + sigmoidf_(iv) * tanhf(gv);
                    float hn = sigmoidf_(ov) * tanhf(cn);
                    if (e) cB1 = cn; else cB0 = cn;
                    h2[e] = hn;
                }
                *(float2*)(houtB_w + (size_t)t * HID) = make_float2(h2[0], h2[1]);
                v4f sv; sv.x = h2[0]; sv.y = h2[1]; sv.z = 0.f; sv.w = tagf;
                const char* ad = (const char*)hp2
                    + ((size_t)(((t + 1) & 1) * 2 + 1) * BB + mybat_w) * 4096 + chunk_idx * 16;
                asm volatile("global_store_dwordx4 %0, %1, off sc0 sc1"
                             :: "v"(ad), "v"(sv) : "memory");
            }
        }
        // no barrier: consumers detect the tagged stores directly
    }
#undef DOTRED
}

// ---------------------------------------------------------------------------
// K3: feats[b][t][k] = bout[k] + [hf(b,t) | hb_rev(b,len-1-t)] . Wout[k,:]
// ---------------------------------------------------------------------------
__global__ __launch_bounds__(64) void k_feats(
    const int* __restrict__ lengths,
    const float* __restrict__ hbuf,  // [2][B][T][512]
    const float* __restrict__ Wout,  // [20][1024]
    const float* __restrict__ bout,  // [20]
    float* __restrict__ feats)       // [B][T][20]
{
    const int bt = blockIdx.x;
    const int b = bt >> 8, t = bt & 255;
    const int len = lengths[b];
    if (t >= len) return;

    __shared__ float hc[2 * HID];
    const float* hf = hbuf + ((size_t)b * TT + t) * HID;
    const float* hb = hbuf + ((size_t)(BB + b) * TT + (len - 1 - t)) * HID;
    const int tid = threadIdx.x;
    for (int i = tid; i < HID / 4; i += 64)
        ((float4*)hc)[i] = ((const float4*)hf)[i];
    for (int i = tid; i < HID / 4; i += 64)
        ((float4*)(hc + HID))[i] = ((const float4*)hb)[i];
    __syncthreads();

    if (tid < KTAGS) {
        float d = bout[tid];
        const float* wr = Wout + (size_t)tid * (2 * HID);
        #pragma unroll 4
        for (int i = 0; i < 2 * HID; i++) d = fmaf(hc[i], wr[i], d);
        feats[(size_t)bt * KTAGS + tid] = d;
    }
}

// ---------------------------------------------------------------------------
// K4: Viterbi forward + terminal + right-aligned backtrack.
// ---------------------------------------------------------------------------
__global__ __launch_bounds__(64) void k_viterbi(
    const int* __restrict__ lengths,
    const float* __restrict__ trans,  // [20][20]
    const float* __restrict__ feats,  // [B][T][20]
    int* __restrict__ bptr,           // [B][T][20]
    float* __restrict__ out)          // [32 scores][32*257 path]
{
    const int b = blockIdx.x;
    const int len = lengths[b];
    const int tid = threadIdx.x;

    __shared__ float tr[KTAGS * KTAGS];
    __shared__ float fv[KTAGS], fvn[KTAGS];

    for (int i = tid; i < KTAGS * KTAGS; i += 64) tr[i] = trans[i];
    if (tid < KTAGS) fv[tid] = (tid == START_TAG) ? 0.f : NEGV;
    __syncthreads();

    for (int t = 0; t < len; t++) {
        if (tid < KTAGS) {
            float best = -1e30f; int bi = 0;
            #pragma unroll
            for (int p = 0; p < KTAGS; p++) {
                float s = fv[p] + tr[tid * KTAGS + p];
                if (s > best) { best = s; bi = p; }
            }
            fvn[tid] = best + feats[((size_t)b * TT + t) * KTAGS + tid];
            bptr[((size_t)b * TT + t) * KTAGS + tid] = bi;
        }
        __syncthreads();
        if (tid < KTAGS) fv[tid] = fvn[tid];
        __syncthreads();
    }

    if (tid < KTAGS) fvn[tid] = fv[tid] + tr[END_TAG * KTAGS + tid];
    __syncthreads();

    if (tid == 0) {
        int bt_ = 0; float best = fvn[0];
        for (int k = 1; k < KTAGS; k++)
            if (fvn[k] > best) { best = fvn[k]; bt_ = k; }
        out[b] = best;
        float* path = out + BB + (size_t)b * (TT + 1);
        path[TT] = (float)bt_;
        int cur = bt_;
        for (int t = TT - 1; t >= 0; t--) {
            int src = t - (TT - len);
            if (src >= 0) cur = bptr[((size_t)b * TT + src) * KTAGS + cur];
            else          cur = KTAGS;
            path[t] = (float)cur;
        }
    }
}

// ---------------------------------------------------------------------------
extern "C" void kernel_launch(void* const* d_in, const int* in_sizes, int n_in,
                              void* d_out, int out_size, void* d_ws, size_t ws_size,
                              hipStream_t stream) {
    const int*   sentence = (const int*)d_in[0];
    const int*   lengths  = (const int*)d_in[1];
    const float* emb      = (const float*)d_in[2];
    const float* Wf_ih    = (const float*)d_in[3];
    const float* Wf_hh    = (const float*)d_in[4];
    const float* bf_ih    = (const float*)d_in[5];
    const float* bf_hh    = (const float*)d_in[6];
    const float* Wb_ih    = (const float*)d_in[7];
    const float* Wb_hh    = (const float*)d_in[8];
    const float* bb_ih    = (const float*)d_in[9];
    const float* bb_hh    = (const float*)d_in[10];
    const float* Wout     = (const float*)d_in[11];
    const float* bout     = (const float*)d_in[12];
    const float* trans    = (const float*)d_in[13];
    float* out = (float*)d_out;

    // workspace layout
    float*    hp2   = (float*)d_ws;                            // 131072 floats (512KB)
    float*    pre   = hp2 + 131072;                            // 2*32*256*2048 floats
    float*    hbuf  = pre + (size_t)2 * BB * TT * G4;          // 2*32*256*512
    float*    feats = hbuf + (size_t)2 * BB * TT * HID;        // 32*256*20
    int*      bptr  = (int*)(feats + (size_t)BB * TT * KTAGS); // 32*256*20

    // zero the tagged exchange buffer (tag 0 == expected at t=0, h(0)=0)
    (void)hipMemsetAsync(d_ws, 0, 131072 * 4, stream);

    hipLaunchKernelGGL(k_pre_gemm, dim3(G4 / 64, (BB * TT) / 64, 2), dim3(256), 0, stream,
                       sentence, lengths, emb, Wf_ih, bf_ih, bf_hh, Wb_ih, bb_ih, bb_hh, pre);
    hipLaunchKernelGGL(k_lstm_persist, dim3(256), dim3(512), 0, stream,
                       lengths, Wf_hh, Wb_hh, pre, hp2, hbuf);
    hipLaunchKernelGGL(k_feats, dim3(BB * TT), dim3(64), 0, stream,
                       lengths, hbuf, Wout, bout, feats);
    hipLaunchKernelGGL(k_viterbi, dim3(BB), dim3(64), 0, stream,
                       lengths, trans, feats, bptr, out);
}

// Round 14
// 2581.497 us; speedup vs baseline: 1.1813x; 1.1813x over previous
//
#include <hip/hip_runtime.h>
#include <math.h>

#define VOCAB 50000
#define EMB 256
#define HID 512
#define G4 2048   // 4*HID
#define KTAGS 20
#define START_TAG 18
#define END_TAG 19
#define BB 32
#define TT 256
#define NEGV -10000.0f
#define HSROW 644   // 640 phys floats per row + 4 skew
#define XSROW 264   // 256 + 8 skew

__device__ __forceinline__ float sigmoidf_(float x) { return 1.0f / (1.0f + expf(-x)); }

// ---------------------------------------------------------------------------
// K2: persistent batched LSTM, dual-dir merged phases + FUSED input GEMM.
//   256 WGs x 512 thr (1/CU). WG = (8-unit slice, 8-batch sorted group).
//   Per step: prefetch x=emb[tok] rows (barrier-independent!), combined
//   cohort barrier wait (F on lanes 0-7, B on 8-15), one staging round-trip
//   (8F+8B h-rows, sc1), dot = Whh.h + Wih.x (weights in VGPRs), gates with
//   bias regs, one drain, both arrives. k_pre_gemm is DELETED.
// ---------------------------------------------------------------------------
__global__ __launch_bounds__(512, 1) void k_lstm_persist(
    const int* __restrict__ lengths,
    const int* __restrict__ sentence,  // [32][256]
    const float* __restrict__ emb,     // [VOCAB][256]
    const float* __restrict__ Wf_hh, const float* __restrict__ Wb_hh,
    const float* __restrict__ Wf_ih, const float* __restrict__ Wb_ih,
    const float* __restrict__ bf_ih, const float* __restrict__ bf_hh,
    const float* __restrict__ bb_ih, const float* __restrict__ bb_hh,
    float* __restrict__ hping,         // [2 parity][2 dir][32][512]
    unsigned* __restrict__ bar,        // [8 cohorts][8 lines x 16 uints]
    float* __restrict__ hbuf)          // [2][32][256][512]
{
    const int wg = blockIdx.x;             // 0..255
    const int slice = wg >> 2;             // unit slice 0..63
    const int grp = wg & 3;                // sorted batch group 0..3
    const int tid = threadIdx.x;
    const int wave = tid >> 6;             // 0..7 = local unit
    const int lane = tid & 63;             // k-slice
    const int u_glob = slice * 8 + wave;   // 0..511

    // recurrent weights: 8 h-floats per lane per gate per dir
    float4 wF[4][2], wB[4][2];
    #pragma unroll
    for (int c = 0; c < 4; c++) {
        const float4* wr = (const float4*)(Wf_hh + (size_t)(c * HID + u_glob) * HID + lane * 8);
        wF[c][0] = wr[0]; wF[c][1] = wr[1];
        const float4* wr2 = (const float4*)(Wb_hh + (size_t)(c * HID + u_glob) * HID + lane * 8);
        wB[c][0] = wr2[0]; wB[c][1] = wr2[1];
    }
    // input weights: 4 x-floats per lane per gate per dir
    float4 iF[4], iB[4];
    #pragma unroll
    for (int c = 0; c < 4; c++) {
        iF[c] = *(const float4*)(Wf_ih + (size_t)(c * HID + u_glob) * EMB + lane * 4);
        iB[c] = *(const float4*)(Wb_ih + (size_t)(c * HID + u_glob) * EMB + lane * 4);
    }
    // biases for this wave's unit
    float bFc[4], bBc[4];
    #pragma unroll
    for (int c = 0; c < 4; c++) {
        bFc[c] = bf_ih[c * HID + u_glob] + bf_hh[c * HID + u_glob];
        bBc[c] = bb_ih[c * HID + u_glob] + bb_hh[c * HID + u_glob];
    }

    __shared__ float hs[16 * HSROW];       // rows 0-7: F h, 8-15: B h
    __shared__ float xs[16 * XSROW];       // rows 0-7: F x, 8-15: B x
    __shared__ float zw[16 * 132];         // [dir*8+wave][gate*33 + j]
    __shared__ int stok[8][TT];            // tokens for group's 8 sorted batches
    __shared__ int lens_raw[32];
    __shared__ int order_s[32];
    __shared__ int lens_s[32];
    __shared__ int nbt_s[TT];

    if (tid < 32) lens_raw[tid] = lengths[tid];
    __syncthreads();
    if (tid < 32) {
        int me = lens_raw[tid], rank = 0;
        #pragma unroll 4
        for (int o = 0; o < 32; o++) {
            int lo = lens_raw[o];
            rank += (lo > me || (lo == me && o < tid)) ? 1 : 0;
        }
        order_s[rank] = tid;
        lens_s[rank] = me;
    }
    if (tid >= 256) {
        int t = tid - 256, c = 0;
        #pragma unroll 4
        for (int b = 0; b < 32; b++) c += (lens_raw[b] > t) ? 1 : 0;
        nbt_s[t] = c;
    }
    __syncthreads();
    // stage tokens for this group's batches (sorted order)
    for (int i = tid; i < 8 * TT; i += 512) {
        int j = i >> 8, c = i & 255;
        stok[j][c] = sentence[order_s[grp * 8 + j] * TT + c];
    }
    __syncthreads();

    const int tlimit = lens_s[grp * 8];

    // gate identity: lanes 0..7 = local sorted pos within group
    const int gj = lane & 7;
    const int g_act = (lane < 8);
    const int p_sort = grp * 8 + gj;
    const int mylen = lens_s[p_sort];
    const int mybat = order_s[p_sort];
    float* houtF = hbuf + (size_t)mybat * TT * HID + u_glob;
    float* houtB = hbuf + (size_t)(BB + mybat) * TT * HID + u_glob;
    float* hpF = hping + (size_t)mybat * HID + u_glob;
    float* hpB = hping + (size_t)(BB + mybat) * HID + u_glob;

    // h staging: 4 slots/thread. kq = tid&127, rA = tid>>7 (0..3)
    const int kq = tid & 127;
    const int rA = tid >> 7;
    const int wbBase = 4 * kq + 4 * (kq >> 2);
    const int sb_lo = order_s[grp * 8 + rA];
    const int sb_hi = order_s[grp * 8 + rA + 4];

    // x staging: row16 = tid>>5 (0..15), part = tid&31 (8 floats each)
    const int xrow = tid >> 5;
    const int xpart = tid & 31;
    const int xjrow = xrow & 7;
    const int xlen = lens_s[grp * 8 + xjrow];
    const bool xisB = xrow >= 8;
    float* xdst = &xs[xrow * XSROW + xpart * 8];

    const int rdoff = 8 * lane + 4 * (lane >> 1);

    float cF = 0.f, cB = 0.f;
    unsigned* barF = bar + grp * 128;
    unsigned* barB = bar + (4 + grp) * 128;
    const int arr_line = (slice & 7) * 16;

#define DOTRED(WREG, WIH, ROWOFF, ZOFF)                                        \
    for (int j = 0; j < jmax; j++) {                                           \
        const float* hb = &hs[((ROWOFF) + j) * HSROW + rdoff];                 \
        float4 h0 = *(const float4*)(hb);                                      \
        float4 h1 = *(const float4*)(hb + 4);                                  \
        float4 xv = *(const float4*)&xs[((ROWOFF) + j) * XSROW + lane * 4];    \
        float a0 = 0.f, a1 = 0.f, a2 = 0.f, a3 = 0.f;                          \
        a0 = fmaf(WREG[0][0].x, h0.x, a0); a0 = fmaf(WREG[0][0].y, h0.y, a0);  \
        a0 = fmaf(WREG[0][0].z, h0.z, a0); a0 = fmaf(WREG[0][0].w, h0.w, a0);  \
        a0 = fmaf(WREG[0][1].x, h1.x, a0); a0 = fmaf(WREG[0][1].y, h1.y, a0);  \
        a0 = fmaf(WREG[0][1].z, h1.z, a0); a0 = fmaf(WREG[0][1].w, h1.w, a0);  \
        a0 = fmaf(WIH[0].x, xv.x, a0);     a0 = fmaf(WIH[0].y, xv.y, a0);      \
        a0 = fmaf(WIH[0].z, xv.z, a0);     a0 = fmaf(WIH[0].w, xv.w, a0);      \
        a1 = fmaf(WREG[1][0].x, h0.x, a1); a1 = fmaf(WREG[1][0].y, h0.y, a1);  \
        a1 = fmaf(WREG[1][0].z, h0.z, a1); a1 = fmaf(WREG[1][0].w, h0.w, a1);  \
        a1 = fmaf(WREG[1][1].x, h1.x, a1); a1 = fmaf(WREG[1][1].y, h1.y, a1);  \
        a1 = fmaf(WREG[1][1].z, h1.z, a1); a1 = fmaf(WREG[1][1].w, h1.w, a1);  \
        a1 = fmaf(WIH[1].x, xv.x, a1);     a1 = fmaf(WIH[1].y, xv.y, a1);      \
        a1 = fmaf(WIH[1].z, xv.z, a1);     a1 = fmaf(WIH[1].w, xv.w, a1);      \
        a2 = fmaf(WREG[2][0].x, h0.x, a2); a2 = fmaf(WREG[2][0].y, h0.y, a2);  \
        a2 = fmaf(WREG[2][0].z, h0.z, a2); a2 = fmaf(WREG[2][0].w, h0.w, a2);  \
        a2 = fmaf(WREG[2][1].x, h1.x, a2); a2 = fmaf(WREG[2][1].y, h1.y, a2);  \
        a2 = fmaf(WREG[2][1].z, h1.z, a2); a2 = fmaf(WREG[2][1].w, h1.w, a2);  \
        a2 = fmaf(WIH[2].x, xv.x, a2);     a2 = fmaf(WIH[2].y, xv.y, a2);      \
        a2 = fmaf(WIH[2].z, xv.z, a2);     a2 = fmaf(WIH[2].w, xv.w, a2);      \
        a3 = fmaf(WREG[3][0].x, h0.x, a3); a3 = fmaf(WREG[3][0].y, h0.y, a3);  \
        a3 = fmaf(WREG[3][0].z, h0.z, a3); a3 = fmaf(WREG[3][0].w, h0.w, a3);  \
        a3 = fmaf(WREG[3][1].x, h1.x, a3); a3 = fmaf(WREG[3][1].y, h1.y, a3);  \
        a3 = fmaf(WREG[3][1].z, h1.z, a3); a3 = fmaf(WREG[3][1].w, h1.w, a3);  \
        a3 = fmaf(WIH[3].x, xv.x, a3);     a3 = fmaf(WIH[3].y, xv.y, a3);      \
        a3 = fmaf(WIH[3].z, xv.z, a3);     a3 = fmaf(WIH[3].w, xv.w, a3);      \
        bool lo32 = (lane & 32) == 0;                                          \
        float tA = __shfl_xor(lo32 ? a2 : a0, 32);                             \
        float tB = __shfl_xor(lo32 ? a3 : a1, 32);                             \
        float rAq = (lo32 ? a0 : a2) + tA;                                     \
        float rBq = (lo32 ? a1 : a3) + tB;                                     \
        bool lo16 = (lane & 16) == 0;                                          \
        float tC = __shfl_xor(lo16 ? rBq : rAq, 16);                           \
        float r  = (lo16 ? rAq : rBq) + tC;                                    \
        r += __shfl_xor(r, 8);                                                 \
        r += __shfl_xor(r, 4);                                                 \
        r += __shfl_xor(r, 2);                                                 \
        r += __shfl_xor(r, 1);                                                 \
        if ((lane & 15) == 0)                                                  \
            zw[((ZOFF) + wave) * 132 + (lane >> 4) * 33 + j] = r;              \
    }

    for (int t = 0; t < tlimit; t++) {
        const int nbt = nbt_s[t];
        const int jmax = min(max(nbt - grp * 8, 0), 8);
        const int act = g_act && (t < mylen);
        const int pred_lo = (grp * 8 + rA < nbt);
        const int pred_hi = (grp * 8 + rA + 4 < nbt);

        // ---- prefetch x rows (barrier-independent) ----
        int posx = xisB ? ((t < xlen) ? xlen - 1 - t : t) : t;
        const float* xr = emb + (size_t)stok[xjrow][posx] * EMB + xpart * 8;
        float4 xa = *(const float4*)xr;
        float4 xb2 = *(const float4*)(xr + 4);

        // ---- combined barrier wait: F lines on lanes 0-7, B on 8-15 ----
        if (t > 0 && wave == 0) {
            const unsigned tgt = (unsigned)t * 8u;
            const unsigned* cp = (lane < 8) ? (barF + lane * 16)
                               : (lane < 16) ? (barB + (lane - 8) * 16)
                               : barF;
            bool mydone = (lane >= 16);
            while (true) {
                if (!mydone)
                    mydone = __hip_atomic_load(cp, __ATOMIC_RELAXED,
                                               __HIP_MEMORY_SCOPE_AGENT) >= tgt;
                if (__ballot(mydone) == ~0ull) break;
                __builtin_amdgcn_s_sleep(1);
            }
        }
        __syncthreads();

        // ---- stage h(t) for BOTH dirs: 4 sc1 dwordx4 loads, one vmcnt ----
        {
            const char* baseF = (const char*)hping + (size_t)((t & 1) * 2) * BB * HID * 4;
            const char* baseB = baseF + (size_t)BB * HID * 4;
            const char* fb = baseF + (tid & 63) * 16;
            const char* a0 = pred_lo ? baseF + sb_lo * 2048 + kq * 16 : fb;
            const char* a1 = pred_hi ? baseF + sb_hi * 2048 + kq * 16 : fb;
            const char* a2 = pred_lo ? baseB + sb_lo * 2048 + kq * 16 : fb;
            const char* a3 = pred_hi ? baseB + sb_hi * 2048 + kq * 16 : fb;
            float4 u0, u1, u2, u3;
            asm volatile(
                "global_load_dwordx4 %0, %4, off sc0 sc1\n\t"
                "global_load_dwordx4 %1, %5, off sc0 sc1\n\t"
                "global_load_dwordx4 %2, %6, off sc0 sc1\n\t"
                "global_load_dwordx4 %3, %7, off sc0 sc1\n\t"
                "s_waitcnt vmcnt(0)"
                : "=&v"(u0), "=&v"(u1), "=&v"(u2), "=&v"(u3)
                : "v"(a0), "v"(a1), "v"(a2), "v"(a3)
                : "memory");
            *(float4*)&hs[(rA     ) * HSROW + wbBase] = u0;
            *(float4*)&hs[(rA +  4) * HSROW + wbBase] = u1;
            *(float4*)&hs[(rA +  8) * HSROW + wbBase] = u2;
            *(float4*)&hs[(rA + 12) * HSROW + wbBase] = u3;
            *(float4*)xdst = xa;
            *(float4*)(xdst + 4) = xb2;
        }
        __syncthreads();

        // ---- dots: F then B (Whh.h + Wih.x fused) ----
        DOTRED(wF, iF, 0, 0);
        DOTRED(wB, iB, 8, 8);

        // ---- gates: both dirs (same-wave zw) ----
        if (act) {
            {
                float iv = zw[wave * 132 +  0 + gj] + bFc[0];
                float fv = zw[wave * 132 + 33 + gj] + bFc[1];
                float gv = zw[wave * 132 + 66 + gj] + bFc[2];
                float ov = zw[wave * 132 + 99 + gj] + bFc[3];
                float cn = sigmoidf_(fv) * cF + sigmoidf_(iv) * tanhf(gv);
                float hn = sigmoidf_(ov) * tanhf(cn);
                cF = cn;
                houtF[(size_t)t * HID] = hn;
                __hip_atomic_store(hpF + (size_t)(((t + 1) & 1) * 2) * BB * HID,
                                   hn, __ATOMIC_RELAXED, __HIP_MEMORY_SCOPE_AGENT);
            }
            {
                float iv = zw[(8 + wave) * 132 +  0 + gj] + bBc[0];
                float fv = zw[(8 + wave) * 132 + 33 + gj] + bBc[1];
                float gv = zw[(8 + wave) * 132 + 66 + gj] + bBc[2];
                float ov = zw[(8 + wave) * 132 + 99 + gj] + bBc[3];
                float cn = sigmoidf_(fv) * cB + sigmoidf_(iv) * tanhf(gv);
                float hn = sigmoidf_(ov) * tanhf(cn);
                cB = cn;
                houtB[(size_t)t * HID] = hn;
                __hip_atomic_store(hpB + (size_t)(((t + 1) & 1) * 2) * BB * HID,
                                   hn, __ATOMIC_RELAXED, __HIP_MEMORY_SCOPE_AGENT);
            }
        }

        // ---- single drain + both arrives ----
        __syncthreads();   // all sc1 stores drained; hs/xs free for next stage
        if (t < tlimit - 1) {
            if (tid == 0)
                __hip_atomic_fetch_add(barF + arr_line, 1u,
                                       __ATOMIC_RELAXED, __HIP_MEMORY_SCOPE_AGENT);
            if (tid == 1)
                __hip_atomic_fetch_add(barB + arr_line, 1u,
                                       __ATOMIC_RELAXED, __HIP_MEMORY_SCOPE_AGENT);
        }
    }
#undef DOTRED
}

// ---------------------------------------------------------------------------
// K3: feats[b][t][k] = bout[k] + [hf(b,t) | hb_rev(b,len-1-t)] . Wout[k,:]
// ---------------------------------------------------------------------------
__global__ __launch_bounds__(64) void k_feats(
    const int* __restrict__ lengths,
    const float* __restrict__ hbuf,  // [2][B][T][512]
    const float* __restrict__ Wout,  // [20][1024]
    const float* __restrict__ bout,  // [20]
    float* __restrict__ feats)       // [B][T][20]
{
    const int bt = blockIdx.x;
    const int b = bt >> 8, t = bt & 255;
    const int len = lengths[b];
    if (t >= len) return;

    __shared__ float hc[2 * HID];
    const float* hf = hbuf + ((size_t)b * TT + t) * HID;
    const float* hb = hbuf + ((size_t)(BB + b) * TT + (len - 1 - t)) * HID;
    const int tid = threadIdx.x;
    for (int i = tid; i < HID / 4; i += 64)
        ((float4*)hc)[i] = ((const float4*)hf)[i];
    for (int i = tid; i < HID / 4; i += 64)
        ((float4*)(hc + HID))[i] = ((const float4*)hb)[i];
    __syncthreads();

    if (tid < KTAGS) {
        float d = bout[tid];
        const float* wr = Wout + (size_t)tid * (2 * HID);
        #pragma unroll 4
        for (int i = 0; i < 2 * HID; i++) d = fmaf(hc[i], wr[i], d);
        feats[(size_t)bt * KTAGS + tid] = d;
    }
}

// ---------------------------------------------------------------------------
// K4: Viterbi forward + terminal + right-aligned backtrack.
// ---------------------------------------------------------------------------
__global__ __launch_bounds__(64) void k_viterbi(
    const int* __restrict__ lengths,
    const float* __restrict__ trans,  // [20][20]
    const float* __restrict__ feats,  // [B][T][20]
    int* __restrict__ bptr,           // [B][T][20]
    float* __restrict__ out)          // [32 scores][32*257 path]
{
    const int b = blockIdx.x;
    const int len = lengths[b];
    const int tid = threadIdx.x;

    __shared__ float tr[KTAGS * KTAGS];
    __shared__ float fv[KTAGS], fvn[KTAGS];

    for (int i = tid; i < KTAGS * KTAGS; i += 64) tr[i] = trans[i];
    if (tid < KTAGS) fv[tid] = (tid == START_TAG) ? 0.f : NEGV;
    __syncthreads();

    for (int t = 0; t < len; t++) {
        if (tid < KTAGS) {
            float best = -1e30f; int bi = 0;
            #pragma unroll
            for (int p = 0; p < KTAGS; p++) {
                float s = fv[p] + tr[tid * KTAGS + p];
                if (s > best) { best = s; bi = p; }
            }
            fvn[tid] = best + feats[((size_t)b * TT + t) * KTAGS + tid];
            bptr[((size_t)b * TT + t) * KTAGS + tid] = bi;
        }
        __syncthreads();
        if (tid < KTAGS) fv[tid] = fvn[tid];
        __syncthreads();
    }

    if (tid < KTAGS) fvn[tid] = fv[tid] + tr[END_TAG * KTAGS + tid];
    __syncthreads();

    if (tid == 0) {
        int bt_ = 0; float best = fvn[0];
        for (int k = 1; k < KTAGS; k++)
            if (fvn[k] > best) { best = fvn[k]; bt_ = k; }
        out[b] = best;
        float* path = out + BB + (size_t)b * (TT + 1);
        path[TT] = (float)bt_;
        int cur = bt_;
        for (int t = TT - 1; t >= 0; t--) {
            int src = t - (TT - len);
            if (src >= 0) cur = bptr[((size_t)b * TT + src) * KTAGS + cur];
            else          cur = KTAGS;
            path[t] = (float)cur;
        }
    }
}

// ---------------------------------------------------------------------------
extern "C" void kernel_launch(void* const* d_in, const int* in_sizes, int n_in,
                              void* d_out, int out_size, void* d_ws, size_t ws_size,
                              hipStream_t stream) {
    const int*   sentence = (const int*)d_in[0];
    const int*   lengths  = (const int*)d_in[1];
    const float* emb      = (const float*)d_in[2];
    const float* Wf_ih    = (const float*)d_in[3];
    const float* Wf_hh    = (const float*)d_in[4];
    const float* bf_ih    = (const float*)d_in[5];
    const float* bf_hh    = (const float*)d_in[6];
    const float* Wb_ih    = (const float*)d_in[7];
    const float* Wb_hh    = (const float*)d_in[8];
    const float* bb_ih    = (const float*)d_in[9];
    const float* bb_hh    = (const float*)d_in[10];
    const float* Wout     = (const float*)d_in[11];
    const float* bout     = (const float*)d_in[12];
    const float* trans    = (const float*)d_in[13];
    float* out = (float*)d_out;

    // workspace layout (pre buffer deleted — input GEMM fused into LSTM)
    float*    hping = (float*)d_ws;                            // 65536 floats (256KB)
    unsigned* bar   = (unsigned*)((char*)d_ws + 65536 * 4);    // 4KB (8 cohorts x 8 lines)
    float*    hbuf  = (float*)((char*)d_ws + 65536 * 4 + 4096);// 2*32*256*512 floats
    float*    feats = hbuf + (size_t)2 * BB * TT * HID;        // 32*256*20
    int*      bptr  = (int*)(feats + (size_t)BB * TT * KTAGS); // 32*256*20

    (void)hipMemsetAsync(d_ws, 0, 65536 * 4 + 4096, stream);

    hipLaunchKernelGGL(k_lstm_persist, dim3(256), dim3(512), 0, stream,
                       lengths, sentence, emb, Wf_hh, Wb_hh, Wf_ih, Wb_ih,
                       bf_ih, bf_hh, bb_ih, bb_hh, hping, bar, hbuf);
    hipLaunchKernelGGL(k_feats, dim3(BB * TT), dim3(64), 0, stream,
                       lengths, hbuf, Wout, bout, feats);
    hipLaunchKernelGGL(k_viterbi, dim3(BB), dim3(64), 0, stream,
                       lengths, trans, feats, bptr, out);
}

// Round 15
// 2218.150 us; speedup vs baseline: 1.3748x; 1.1638x over previous
//
#include <hip/hip_runtime.h>
#include <math.h>

#define VOCAB 50000
#define EMB 256
#define HID 512
#define G4 2048   // 4*HID
#define KTAGS 20
#define START_TAG 18
#define END_TAG 19
#define BB 32
#define TT 256
#define NEGV -10000.0f
#define HSROW 644   // 640 phys floats per row + 4 skew
#define XSROW 264   // 256 + 8 skew

__device__ __forceinline__ float sigmoidf_(float x) { return 1.0f / (1.0f + expf(-x)); }

// ---------------------------------------------------------------------------
// K2: persistent batched LSTM, dual-dir merged phases + FUSED input GEMM.
//   256 WGs x 512 thr (1/CU). WG = (8-unit slice, 8-batch sorted group).
//   Per step: prefetch x=emb[tok] rows (barrier-independent), combined
//   cohort barrier wait (F lanes 0-7, B lanes 8-15), one staging round-trip
//   (8F+8B h-rows, sc1), dot = Whh.h + Wih.x (weights in VGPRs), gates,
//   drain, arrives, THEN the hbuf history stores (kept out of the drain).
// ---------------------------------------------------------------------------
__global__ __launch_bounds__(512, 1) void k_lstm_persist(
    const int* __restrict__ lengths,
    const int* __restrict__ sentence,  // [32][256]
    const float* __restrict__ emb,     // [VOCAB][256]
    const float* __restrict__ Wf_hh, const float* __restrict__ Wb_hh,
    const float* __restrict__ Wf_ih, const float* __restrict__ Wb_ih,
    const float* __restrict__ bf_ih, const float* __restrict__ bf_hh,
    const float* __restrict__ bb_ih, const float* __restrict__ bb_hh,
    float* __restrict__ hping,         // [2 parity][2 dir][32][512]
    unsigned* __restrict__ bar,        // [8 cohorts][8 lines x 16 uints]
    float* __restrict__ hbuf)          // [2][32][256][512]
{
    const int wg = blockIdx.x;             // 0..255
    const int slice = wg >> 2;             // unit slice 0..63
    const int grp = wg & 3;                // sorted batch group 0..3
    const int tid = threadIdx.x;
    const int wave = tid >> 6;             // 0..7 = local unit
    const int lane = tid & 63;             // k-slice
    const int u_glob = slice * 8 + wave;   // 0..511

    // recurrent weights: 8 h-floats per lane per gate per dir
    float4 wF[4][2], wB[4][2];
    #pragma unroll
    for (int c = 0; c < 4; c++) {
        const float4* wr = (const float4*)(Wf_hh + (size_t)(c * HID + u_glob) * HID + lane * 8);
        wF[c][0] = wr[0]; wF[c][1] = wr[1];
        const float4* wr2 = (const float4*)(Wb_hh + (size_t)(c * HID + u_glob) * HID + lane * 8);
        wB[c][0] = wr2[0]; wB[c][1] = wr2[1];
    }
    // input weights: 4 x-floats per lane per gate per dir
    float4 iF[4], iB[4];
    #pragma unroll
    for (int c = 0; c < 4; c++) {
        iF[c] = *(const float4*)(Wf_ih + (size_t)(c * HID + u_glob) * EMB + lane * 4);
        iB[c] = *(const float4*)(Wb_ih + (size_t)(c * HID + u_glob) * EMB + lane * 4);
    }
    // biases for this wave's unit
    float bFc[4], bBc[4];
    #pragma unroll
    for (int c = 0; c < 4; c++) {
        bFc[c] = bf_ih[c * HID + u_glob] + bf_hh[c * HID + u_glob];
        bBc[c] = bb_ih[c * HID + u_glob] + bb_hh[c * HID + u_glob];
    }

    __shared__ float hs[16 * HSROW];       // rows 0-7: F h, 8-15: B h
    __shared__ float xs[16 * XSROW];       // rows 0-7: F x, 8-15: B x
    __shared__ float zw[16 * 132];         // [dir*8+wave][gate*33 + j]
    __shared__ int stok[8][TT];            // tokens for group's 8 sorted batches
    __shared__ int lens_raw[32];
    __shared__ int order_s[32];
    __shared__ int lens_s[32];
    __shared__ int nbt_s[TT];

    if (tid < 32) lens_raw[tid] = lengths[tid];
    __syncthreads();
    if (tid < 32) {
        int me = lens_raw[tid], rank = 0;
        #pragma unroll 4
        for (int o = 0; o < 32; o++) {
            int lo = lens_raw[o];
            rank += (lo > me || (lo == me && o < tid)) ? 1 : 0;
        }
        order_s[rank] = tid;
        lens_s[rank] = me;
    }
    if (tid >= 256) {
        int t = tid - 256, c = 0;
        #pragma unroll 4
        for (int b = 0; b < 32; b++) c += (lens_raw[b] > t) ? 1 : 0;
        nbt_s[t] = c;
    }
    __syncthreads();
    for (int i = tid; i < 8 * TT; i += 512) {
        int j = i >> 8, c = i & 255;
        stok[j][c] = sentence[order_s[grp * 8 + j] * TT + c];
    }
    __syncthreads();

    const int tlimit = lens_s[grp * 8];

    // gate identity: lanes 0..7 = local sorted pos within group
    const int gj = lane & 7;
    const int g_act = (lane < 8);
    const int p_sort = grp * 8 + gj;
    const int mylen = lens_s[p_sort];
    const int mybat = order_s[p_sort];
    float* houtF = hbuf + (size_t)mybat * TT * HID + u_glob;
    float* houtB = hbuf + (size_t)(BB + mybat) * TT * HID + u_glob;
    float* hpF = hping + (size_t)mybat * HID + u_glob;
    float* hpB = hping + (size_t)(BB + mybat) * HID + u_glob;

    // h staging: 4 slots/thread. kq = tid&127, rA = tid>>7 (0..3)
    const int kq = tid & 127;
    const int rA = tid >> 7;
    const int wbBase = 4 * kq + 4 * (kq >> 2);
    const int sb_lo = order_s[grp * 8 + rA];
    const int sb_hi = order_s[grp * 8 + rA + 4];

    // x staging: row16 = tid>>5 (0..15), part = tid&31 (8 floats each)
    const int xrow = tid >> 5;
    const int xpart = tid & 31;
    const int xjrow = xrow & 7;
    const int xlen = lens_s[grp * 8 + xjrow];
    const bool xisB = xrow >= 8;
    float* xdst = &xs[xrow * XSROW + xpart * 8];

    const int rdoff = 8 * lane + 4 * (lane >> 1);

    float cF = 0.f, cB = 0.f;
    unsigned* barF = bar + grp * 128;
    unsigned* barB = bar + (4 + grp) * 128;
    const int arr_line = (slice & 7) * 16;

#define DOTRED(WREG, WIH, ROWOFF, ZOFF)                                        \
    for (int j = 0; j < jmax; j++) {                                           \
        const float* hb = &hs[((ROWOFF) + j) * HSROW + rdoff];                 \
        float4 h0 = *(const float4*)(hb);                                      \
        float4 h1 = *(const float4*)(hb + 4);                                  \
        float4 xv = *(const float4*)&xs[((ROWOFF) + j) * XSROW + lane * 4];    \
        float a0 = 0.f, a1 = 0.f, a2 = 0.f, a3 = 0.f;                          \
        a0 = fmaf(WREG[0][0].x, h0.x, a0); a0 = fmaf(WREG[0][0].y, h0.y, a0);  \
        a0 = fmaf(WREG[0][0].z, h0.z, a0); a0 = fmaf(WREG[0][0].w, h0.w, a0);  \
        a0 = fmaf(WREG[0][1].x, h1.x, a0); a0 = fmaf(WREG[0][1].y, h1.y, a0);  \
        a0 = fmaf(WREG[0][1].z, h1.z, a0); a0 = fmaf(WREG[0][1].w, h1.w, a0);  \
        a0 = fmaf(WIH[0].x, xv.x, a0);     a0 = fmaf(WIH[0].y, xv.y, a0);      \
        a0 = fmaf(WIH[0].z, xv.z, a0);     a0 = fmaf(WIH[0].w, xv.w, a0);      \
        a1 = fmaf(WREG[1][0].x, h0.x, a1); a1 = fmaf(WREG[1][0].y, h0.y, a1);  \
        a1 = fmaf(WREG[1][0].z, h0.z, a1); a1 = fmaf(WREG[1][0].w, h0.w, a1);  \
        a1 = fmaf(WREG[1][1].x, h1.x, a1); a1 = fmaf(WREG[1][1].y, h1.y, a1);  \
        a1 = fmaf(WREG[1][1].z, h1.z, a1); a1 = fmaf(WREG[1][1].w, h1.w, a1);  \
        a1 = fmaf(WIH[1].x, xv.x, a1);     a1 = fmaf(WIH[1].y, xv.y, a1);      \
        a1 = fmaf(WIH[1].z, xv.z, a1);     a1 = fmaf(WIH[1].w, xv.w, a1);      \
        a2 = fmaf(WREG[2][0].x, h0.x, a2); a2 = fmaf(WREG[2][0].y, h0.y, a2);  \
        a2 = fmaf(WREG[2][0].z, h0.z, a2); a2 = fmaf(WREG[2][0].w, h0.w, a2);  \
        a2 = fmaf(WREG[2][1].x, h1.x, a2); a2 = fmaf(WREG[2][1].y, h1.y, a2);  \
        a2 = fmaf(WREG[2][1].z, h1.z, a2); a2 = fmaf(WREG[2][1].w, h1.w, a2);  \
        a2 = fmaf(WIH[2].x, xv.x, a2);     a2 = fmaf(WIH[2].y, xv.y, a2);      \
        a2 = fmaf(WIH[2].z, xv.z, a2);     a2 = fmaf(WIH[2].w, xv.w, a2);      \
        a3 = fmaf(WREG[3][0].x, h0.x, a3); a3 = fmaf(WREG[3][0].y, h0.y, a3);  \
        a3 = fmaf(WREG[3][0].z, h0.z, a3); a3 = fmaf(WREG[3][0].w, h0.w, a3);  \
        a3 = fmaf(WREG[3][1].x, h1.x, a3); a3 = fmaf(WREG[3][1].y, h1.y, a3);  \
        a3 = fmaf(WREG[3][1].z, h1.z, a3); a3 = fmaf(WREG[3][1].w, h1.w, a3);  \
        a3 = fmaf(WIH[3].x, xv.x, a3);     a3 = fmaf(WIH[3].y, xv.y, a3);      \
        a3 = fmaf(WIH[3].z, xv.z, a3);     a3 = fmaf(WIH[3].w, xv.w, a3);      \
        bool lo32 = (lane & 32) == 0;                                          \
        float tA = __shfl_xor(lo32 ? a2 : a0, 32);                             \
        float tB = __shfl_xor(lo32 ? a3 : a1, 32);                             \
        float rAq = (lo32 ? a0 : a2) + tA;                                     \
        float rBq = (lo32 ? a1 : a3) + tB;                                     \
        bool lo16 = (lane & 16) == 0;                                          \
        float tC = __shfl_xor(lo16 ? rBq : rAq, 16);                           \
        float r  = (lo16 ? rAq : rBq) + tC;                                    \
        r += __shfl_xor(r, 8);                                                 \
        r += __shfl_xor(r, 4);                                                 \
        r += __shfl_xor(r, 2);                                                 \
        r += __shfl_xor(r, 1);                                                 \
        if ((lane & 15) == 0)                                                  \
            zw[((ZOFF) + wave) * 132 + (lane >> 4) * 33 + j] = r;              \
    }

    for (int t = 0; t < tlimit; t++) {
        const int nbt = nbt_s[t];
        const int jmax = min(max(nbt - grp * 8, 0), 8);
        const int act = g_act && (t < mylen);
        const int pred_lo = (grp * 8 + rA < nbt);
        const int pred_hi = (grp * 8 + rA + 4 < nbt);

        // ---- prefetch x rows (barrier-independent) ----
        int posx = xisB ? ((t < xlen) ? xlen - 1 - t : t) : t;
        const float* xr = emb + (size_t)stok[xjrow][posx] * EMB + xpart * 8;
        float4 xa = *(const float4*)xr;
        float4 xb2 = *(const float4*)(xr + 4);

        // ---- combined barrier wait: F lines on lanes 0-7, B on 8-15 ----
        if (t > 0 && wave == 0) {
            const unsigned tgt = (unsigned)t * 8u;
            const unsigned* cp = (lane < 8) ? (barF + lane * 16)
                               : (lane < 16) ? (barB + (lane - 8) * 16)
                               : barF;
            bool mydone = (lane >= 16);
            while (true) {
                if (!mydone)
                    mydone = __hip_atomic_load(cp, __ATOMIC_RELAXED,
                                               __HIP_MEMORY_SCOPE_AGENT) >= tgt;
                if (__ballot(mydone) == ~0ull) break;
                __builtin_amdgcn_s_sleep(1);
            }
        }
        __syncthreads();

        // ---- stage h(t) for BOTH dirs: 4 sc1 dwordx4 loads, one vmcnt ----
        {
            const char* baseF = (const char*)hping + (size_t)((t & 1) * 2) * BB * HID * 4;
            const char* baseB = baseF + (size_t)BB * HID * 4;
            const char* fb = baseF + (tid & 63) * 16;
            const char* a0 = pred_lo ? baseF + sb_lo * 2048 + kq * 16 : fb;
            const char* a1 = pred_hi ? baseF + sb_hi * 2048 + kq * 16 : fb;
            const char* a2 = pred_lo ? baseB + sb_lo * 2048 + kq * 16 : fb;
            const char* a3 = pred_hi ? baseB + sb_hi * 2048 + kq * 16 : fb;
            float4 u0, u1, u2, u3;
            asm volatile(
                "global_load_dwordx4 %0, %4, off sc0 sc1\n\t"
                "global_load_dwordx4 %1, %5, off sc0 sc1\n\t"
                "global_load_dwordx4 %2, %6, off sc0 sc1\n\t"
                "global_load_dwordx4 %3, %7, off sc0 sc1\n\t"
                "s_waitcnt vmcnt(0)"
                : "=&v"(u0), "=&v"(u1), "=&v"(u2), "=&v"(u3)
                : "v"(a0), "v"(a1), "v"(a2), "v"(a3)
                : "memory");
            *(float4*)&hs[(rA     ) * HSROW + wbBase] = u0;
            *(float4*)&hs[(rA +  4) * HSROW + wbBase] = u1;
            *(float4*)&hs[(rA +  8) * HSROW + wbBase] = u2;
            *(float4*)&hs[(rA + 12) * HSROW + wbBase] = u3;
            *(float4*)xdst = xa;
            *(float4*)(xdst + 4) = xb2;
        }
        __syncthreads();

        // ---- dots: F then B (Whh.h + Wih.x fused) ----
        DOTRED(wF, iF, 0, 0);
        DOTRED(wB, iB, 8, 8);

        // ---- gates: both dirs; exchange (hping) stores only ----
        float hnF = 0.f, hnB = 0.f;
        if (act) {
            {
                float iv = zw[wave * 132 +  0 + gj] + bFc[0];
                float fv = zw[wave * 132 + 33 + gj] + bFc[1];
                float gv = zw[wave * 132 + 66 + gj] + bFc[2];
                float ov = zw[wave * 132 + 99 + gj] + bFc[3];
                float cn = sigmoidf_(fv) * cF + sigmoidf_(iv) * tanhf(gv);
                hnF = sigmoidf_(ov) * tanhf(cn);
                cF = cn;
                __hip_atomic_store(hpF + (size_t)(((t + 1) & 1) * 2) * BB * HID,
                                   hnF, __ATOMIC_RELAXED, __HIP_MEMORY_SCOPE_AGENT);
            }
            {
                float iv = zw[(8 + wave) * 132 +  0 + gj] + bBc[0];
                float fv = zw[(8 + wave) * 132 + 33 + gj] + bBc[1];
                float gv = zw[(8 + wave) * 132 + 66 + gj] + bBc[2];
                float ov = zw[(8 + wave) * 132 + 99 + gj] + bBc[3];
                float cn = sigmoidf_(fv) * cB + sigmoidf_(iv) * tanhf(gv);
                hnB = sigmoidf_(ov) * tanhf(cn);
                cB = cn;
                __hip_atomic_store(hpB + (size_t)(((t + 1) & 1) * 2) * BB * HID,
                                   hnB, __ATOMIC_RELAXED, __HIP_MEMORY_SCOPE_AGENT);
            }
        }

        // ---- drain (exchange stores only) + arrives ----
        __syncthreads();
        if (t < tlimit - 1) {
            if (tid == 0)
                __hip_atomic_fetch_add(barF + arr_line, 1u,
                                       __ATOMIC_RELAXED, __HIP_MEMORY_SCOPE_AGENT);
            if (tid == 1)
                __hip_atomic_fetch_add(barB + arr_line, 1u,
                                       __ATOMIC_RELAXED, __HIP_MEMORY_SCOPE_AGENT);
        }

        // ---- history stores AFTER arrive (latency hides in next wait) ----
        if (act) {
            houtF[(size_t)t * HID] = hnF;
            houtB[(size_t)t * HID] = hnB;
        }
    }
#undef DOTRED
}

// ---------------------------------------------------------------------------
// K3: feats[b][t][k] = bout[k] + [hf(b,t) | hb_rev(b,len-1-t)] . Wout[k,:]
//   One wave per (b,t), 4 waves per block. All 64 lanes: 16-float strip each,
//   20 register accumulators, LDS transpose-reduce.
// ---------------------------------------------------------------------------
__global__ __launch_bounds__(256) void k_feats(
    const int* __restrict__ lengths,
    const float* __restrict__ hbuf,  // [2][B][T][512]
    const float* __restrict__ Wout,  // [20][1024]
    const float* __restrict__ bout,  // [20]
    float* __restrict__ feats)       // [B][T][20]
{
    const int w = threadIdx.x >> 6;        // wave in block 0..3
    const int lane = threadIdx.x & 63;
    const int idx = blockIdx.x * 4 + w;    // (b*TT + t)
    const int b = idx >> 8, t = idx & 255;
    const int len = lengths[b];

    __shared__ float red[4][64][21];

    float acc[KTAGS];
    bool active = (t < len);
    if (active) {
        const int ofs = lane * 16;         // position in 1024-concat
        const float* src = (ofs < HID)
            ? hbuf + ((size_t)b * TT + t) * HID + ofs
            : hbuf + ((size_t)(BB + b) * TT + (len - 1 - t)) * HID + (ofs - HID);
        float x[16];
        #pragma unroll
        for (int q = 0; q < 4; q++) {
            float4 v = *(const float4*)(src + 4 * q);
            x[4 * q] = v.x; x[4 * q + 1] = v.y; x[4 * q + 2] = v.z; x[4 * q + 3] = v.w;
        }
        #pragma unroll
        for (int k = 0; k < KTAGS; k++) {
            const float* wr = Wout + (size_t)k * (2 * HID) + ofs;
            float a = 0.f;
            #pragma unroll
            for (int q = 0; q < 4; q++) {
                float4 v = *(const float4*)(wr + 4 * q);
                a = fmaf(x[4 * q], v.x, a);
                a = fmaf(x[4 * q + 1], v.y, a);
                a = fmaf(x[4 * q + 2], v.z, a);
                a = fmaf(x[4 * q + 3], v.w, a);
            }
            acc[k] = a;
        }
    } else {
        #pragma unroll
        for (int k = 0; k < KTAGS; k++) acc[k] = 0.f;
    }
    #pragma unroll
    for (int k = 0; k < KTAGS; k++) red[w][lane][k] = acc[k];
    __syncthreads();

    if (active && lane < KTAGS) {
        float s = bout[lane];
        #pragma unroll 8
        for (int l = 0; l < 64; l++) s += red[w][l][lane];
        feats[(size_t)idx * KTAGS + lane] = s;
    }
}

// ---------------------------------------------------------------------------
// K4: Viterbi forward (fv double-buffered, feats prefetch, 1 sync/step) +
//     terminal + backtrack entirely from LDS backpointers.
// ---------------------------------------------------------------------------
__global__ __launch_bounds__(64) void k_viterbi(
    const int* __restrict__ lengths,
    const float* __restrict__ trans,  // [20][20]
    const float* __restrict__ feats,  // [B][T][20]
    float* __restrict__ out)          // [32 scores][32*257 path]
{
    const int b = blockIdx.x;
    const int len = lengths[b];
    const int tid = threadIdx.x;

    __shared__ float tr[KTAGS * KTAGS];
    __shared__ float fvb[2][KTAGS];
    __shared__ int   bp[TT][KTAGS];    // 20 KB
    __shared__ float term[KTAGS];

    for (int i = tid; i < KTAGS * KTAGS; i += 64) tr[i] = trans[i];
    if (tid < KTAGS) fvb[0][tid] = (tid == START_TAG) ? 0.f : NEGV;
    __syncthreads();

    float ft = (tid < KTAGS) ? feats[((size_t)b * TT) * KTAGS + tid] : 0.f;
    for (int t = 0; t < len; t++) {
        float ftn = (tid < KTAGS && t + 1 < len)
                  ? feats[((size_t)b * TT + t + 1) * KTAGS + tid] : 0.f;
        if (tid < KTAGS) {
            const float* fvc = fvb[t & 1];
            float best = -1e30f; int bi = 0;
            #pragma unroll
            for (int p = 0; p < KTAGS; p++) {
                float s = fvc[p] + tr[tid * KTAGS + p];
                if (s > best) { best = s; bi = p; }
            }
            fvb[(t + 1) & 1][tid] = best + ft;
            bp[t][tid] = bi;
        }
        ft = ftn;
        __syncthreads();
    }

    if (tid < KTAGS) term[tid] = fvb[len & 1][tid] + tr[END_TAG * KTAGS + tid];
    __syncthreads();

    if (tid == 0) {
        int bt_ = 0; float best = term[0];
        for (int k = 1; k < KTAGS; k++)
            if (term[k] > best) { best = term[k]; bt_ = k; }
        out[b] = best;
        float* path = out + BB + (size_t)b * (TT + 1);
        path[TT] = (float)bt_;
        int cur = bt_;
        for (int t = TT - 1; t >= 0; t--) {
            int src = t - (TT - len);
            if (src >= 0) cur = bp[src][cur];
            else          cur = KTAGS;
            path[t] = (float)cur;
        }
    }
}

// ---------------------------------------------------------------------------
extern "C" void kernel_launch(void* const* d_in, const int* in_sizes, int n_in,
                              void* d_out, int out_size, void* d_ws, size_t ws_size,
                              hipStream_t stream) {
    const int*   sentence = (const int*)d_in[0];
    const int*   lengths  = (const int*)d_in[1];
    const float* emb      = (const float*)d_in[2];
    const float* Wf_ih    = (const float*)d_in[3];
    const float* Wf_hh    = (const float*)d_in[4];
    const float* bf_ih    = (const float*)d_in[5];
    const float* bf_hh    = (const float*)d_in[6];
    const float* Wb_ih    = (const float*)d_in[7];
    const float* Wb_hh    = (const float*)d_in[8];
    const float* bb_ih    = (const float*)d_in[9];
    const float* bb_hh    = (const float*)d_in[10];
    const float* Wout     = (const float*)d_in[11];
    const float* bout     = (const float*)d_in[12];
    const float* trans    = (const float*)d_in[13];
    float* out = (float*)d_out;

    // workspace layout
    float*    hping = (float*)d_ws;                            // 65536 floats (256KB)
    unsigned* bar   = (unsigned*)((char*)d_ws + 65536 * 4);    // 4KB (8 cohorts x 8 lines)
    float*    hbuf  = (float*)((char*)d_ws + 65536 * 4 + 4096);// 2*32*256*512 floats
    float*    feats = hbuf + (size_t)2 * BB * TT * HID;        // 32*256*20

    (void)hipMemsetAsync(d_ws, 0, 65536 * 4 + 4096, stream);

    hipLaunchKernelGGL(k_lstm_persist, dim3(256), dim3(512), 0, stream,
                       lengths, sentence, emb, Wf_hh, Wb_hh, Wf_ih, Wb_ih,
                       bf_ih, bf_hh, bb_ih, bb_hh, hping, bar, hbuf);
    hipLaunchKernelGGL(k_feats, dim3(BB * TT / 4), dim3(256), 0, stream,
                       lengths, hbuf, Wout, bout, feats);
    hipLaunchKernelGGL(k_viterbi, dim3(BB), dim3(64), 0, stream,
                       lengths, trans, feats, out);
}